// Round 4
// baseline (268.060 us; speedup 1.0000x reference)
//
#include <hip/hip_runtime.h>
#include <hip/hip_bf16.h>
#include <hip/hip_fp16.h>

// Problem constants (fixed by setup_inputs)
#define NQ   5440
#define NB   8
#define DIM  256
#define NH   8
#define CHN  32
#define NLV  4
#define NPT  4
#define MTOT (NB * NQ)   // 43520

typedef __attribute__((ext_vector_type(8))) short s16x8;   // 8 x 16-bit (4 VGPRs)
typedef __attribute__((ext_vector_type(4))) float f32x4;
typedef unsigned short ushort_t;

// bf16 weight-buffer segment offsets (elements): [W_val | W_off | W_attn | W_out]
#define WVAL 0
#define WOFF 65536
#define WATT 131072
#define WOUT 163840
#define WTOT 229376
#define QTOT (MTOT * DIM)   // 11,141,120 elements (query; inputf same size)

__device__ __forceinline__ short f2bf(float x) {
    union { __hip_bfloat16 b; short s; } u;
    u.b = __float2bfloat16(x);
    return u.s;
}

// async 16B global->LDS copy; LDS dst = wave-uniform base + lane*16
__device__ __forceinline__ void gload_lds16(const void* g, void* l) {
    __builtin_amdgcn_global_load_lds(
        (const __attribute__((address_space(1))) unsigned int*)g,
        (__attribute__((address_space(3))) unsigned int*)l, 16, 0, 0);
}

__device__ __forceinline__ void cvt8b(const float* s, ushort_t* d) {
    f32x4 a = *(const f32x4*)s, b = *(const f32x4*)(s + 4);
    s16x8 v;
#pragma unroll
    for (int e = 0; e < 4; ++e) { v[e] = f2bf(a[e]); v[e + 4] = f2bf(b[e]); }
    *(s16x8*)d = v;
}

// one-time fp32 -> bf16: weights (0.9 MB) + query (44.6 MB) + inputf (44.6 MB).
// Pure streaming; makes every GEMM A-operand a bf16 async-DMA path.
__global__ __launch_bounds__(256) void cvt_all(const float* __restrict__ wv,
                                               const float* __restrict__ wo,
                                               const float* __restrict__ wa,
                                               const float* __restrict__ wu,
                                               const float* __restrict__ query,
                                               const float* __restrict__ inputf,
                                               ushort_t* __restrict__ wb,
                                               ushort_t* __restrict__ qb,
                                               ushort_t* __restrict__ ib) {
    const int i = (blockIdx.x * 256 + threadIdx.x) * 8;
    if (i < WTOT) {
        const float* src;
        int off;
        if (i < WOFF)      { src = wv; off = WVAL; }
        else if (i < WATT) { src = wo; off = WOFF; }
        else if (i < WOUT) { src = wa; off = WATT; }
        else               { src = wu; off = WOUT; }
        cvt8b(src + (i - off), wb + i);
    } else {
        const int j = i - WTOT;
        if (j < QTOT) cvt8b(query + j, qb + j);
        else {
            const int k = j - QTOT;
            if (k < QTOT) cvt8b(inputf + k, ib + k);
        }
    }
}

__device__ __forceinline__ void stC(float* p, float v) { *p = v; }
__device__ __forceinline__ void stC(__half* p, float v) { *p = __float2half(v); }

// C[m, jloc] = sum_k A[rowBase+m, k] * Wt[jloc, k] + biasT[jloc]
// 128x128 tile, BK=32, 256 threads (2x2 waves), 4x4 16x16x32 bf16 MFMA frags.
// 2-phase double-buffer: issue K-step ks+1's DMA before ks's MFMAs; one
// vmcnt-draining barrier per step. LDS = 2 x (8+8) KB = 32 KB -> with
// launch_bounds(256,4) (VGPR<=128) 4 blocks/CU = 16 waves/CU.
// Swizzle (4 slots/row, row = 64B): row r's k-group g lives at slot (g+r)&3.
// Staging is lane-linear 16B DMA with inverse-swizzled SOURCE address;
// fragment ds_read_b128: bank base = 16*(R&1) + slot*4 -> 8 distinct 16B
// positions over 16 lanes = 2-way alias (free).
template <typename CT>
__device__ __forceinline__ void gemm_job(ushort_t* __restrict__ AsB,
                                         ushort_t* __restrict__ WsB,
                                         const ushort_t* __restrict__ A,
                                         const ushort_t* __restrict__ Wt,
                                         const float* __restrict__ biasT,
                                         CT* __restrict__ Ct, int ldC, int rowBase) {
    const int t = threadIdx.x;
    const int lane = t & 63, w = t >> 6;
    const int wm = w >> 1, wn = w & 1;
    const int lr = lane & 15, quad = lane >> 4;

    f32x4 acc[4][4];
#pragma unroll
    for (int i = 0; i < 4; ++i)
#pragma unroll
        for (int j = 0; j < 4; ++j)
#pragma unroll
            for (int r = 0; r < 4; ++r) acc[i][j][r] = 0.f;

    // Stage K-step ks into buffer b: 512 chunks (16B) per matrix, 2/thread.
    auto issue = [&](int ks, int b) {
        ushort_t* Ad = AsB + b * 4096;
        ushort_t* Wd = WsB + b * 4096;
#pragma unroll
        for (int i = 0; i < 2; ++i) {
            const int c = t + i * 256;          // chunk id 0..511
            const int r = c >> 2, s = c & 3;
            const int g = (s - r) & 3;          // inverse swizzle
            const int ke = ks * 32 + g * 8;     // element k-offset
            gload_lds16(A + (size_t)(rowBase + r) * DIM + ke,
                        &Ad[(size_t)(i * 256 + w * 64) * 8]);
            gload_lds16(Wt + (size_t)r * DIM + ke,
                        &Wd[(size_t)(i * 256 + w * 64) * 8]);
        }
    };

    issue(0, 0);
    __syncthreads();

    for (int ks = 0; ks < 8; ++ks) {
        const int cb = ks & 1, nb = cb ^ 1;
        if (ks < 7) issue(ks + 1, nb);          // loads fly during MFMAs below
        const ushort_t* Ab = AsB + cb * 4096;
        const ushort_t* Wb = WsB + cb * 4096;
        s16x8 afr[4], wfr[4];
        const int G = quad;                     // K=32: k-group = quad
#pragma unroll
        for (int i = 0; i < 4; ++i) {
            const int R = wm * 64 + i * 16 + lr;
            afr[i] = *(const s16x8*)&Ab[(R * 4 + ((G + R) & 3)) * 8];
        }
#pragma unroll
        for (int j = 0; j < 4; ++j) {
            const int R = wn * 64 + j * 16 + lr;
            wfr[j] = *(const s16x8*)&Wb[(R * 4 + ((G + R) & 3)) * 8];
        }
#pragma unroll
        for (int i = 0; i < 4; ++i)
#pragma unroll
            for (int j = 0; j < 4; ++j)
                acc[i][j] = __builtin_amdgcn_mfma_f32_16x16x32_bf16(
                    afr[i], wfr[j], acc[i][j], 0, 0, 0);
        __syncthreads();                        // drains vm+lgkm, barrier
    }

    float bj[4];
#pragma unroll
    for (int j = 0; j < 4; ++j) bj[j] = biasT[wn * 64 + j * 16 + lr];
#pragma unroll
    for (int i = 0; i < 4; ++i)
#pragma unroll
        for (int r = 0; r < 4; ++r) {
            int row = rowBase + wm * 64 + i * 16 + quad * 4 + r;   // D row
#pragma unroll
            for (int j = 0; j < 4; ++j) {
                int col = wn * 64 + j * 16 + lr;                    // D col
                stC(&Ct[(size_t)row * ldC + col], acc[i][j][r] + bj[j]);
            }
        }
}

// Persistent fused GEMM: 1700 jobs = 340 row-panels x 5 col-tiles
// (val 2 | off 2 | attn 1), ordered A-panel-major so the 5 same-A jobs are
// adjacent in dispatch (L2/L3 reuse). grid = 1024 = exactly all-resident at
// 4 blocks/CU; grid-stride kills the tail quantization.
__global__ __launch_bounds__(256, 4) void gemm_all(const ushort_t* __restrict__ qb,
                                                   const ushort_t* __restrict__ ib,
                                                   const ushort_t* __restrict__ wb,
                                                   const float* __restrict__ b_val,
                                                   const float* __restrict__ b_off,
                                                   const float* __restrict__ b_attn,
                                                   __half* __restrict__ bval,
                                                   __half* __restrict__ v_off,
                                                   __half* __restrict__ v_attn) {
    __shared__ ushort_t As[2 * 4096];   // 16 KB (double-buffered A)
    __shared__ ushort_t Ws[2 * 4096];   // 16 KB (double-buffered W)
    for (int job = blockIdx.x; job < 1700; job += gridDim.x) {
        const int jx = job / 5, jy = job - jx * 5;
        const int rowBase = jx * 128;
        const ushort_t* A;
        const ushort_t* Wt;
        const float* bs;
        __half* Ct;
        int ldC;
        if (jy < 2) {
            A = ib;  Wt = wb + WVAL + (size_t)jy * 128 * DIM;
            bs = b_val + jy * 128;  Ct = bval + jy * 128;  ldC = DIM;
        } else if (jy < 4) {
            A = qb;  Wt = wb + WOFF + (size_t)(jy - 2) * 128 * DIM;
            bs = b_off + (jy - 2) * 128;  Ct = v_off + (jy - 2) * 128;  ldC = DIM;
        } else {
            A = qb;  Wt = wb + WATT;
            bs = b_attn;  Ct = v_attn;  ldC = 128;
        }
        gemm_job<__half>(As, Ws, A, Wt, bs, Ct, ldC, rowBase);
    }
}

// 680 blocks -> fully resident at 4 blocks/CU, no tail.
__global__ __launch_bounds__(256, 4) void gemm_out(const ushort_t* __restrict__ A,
                                                   const ushort_t* __restrict__ wb,
                                                   const float* __restrict__ bias,
                                                   float* __restrict__ C) {
    __shared__ ushort_t As[2 * 4096];
    __shared__ ushort_t Ws[2 * 4096];
    gemm_job<float>(As, Ws, A, wb + WOUT + (size_t)blockIdx.y * 128 * DIM,
                    bias + blockIdx.y * 128, C + blockIdx.y * 128, DIM,
                    blockIdx.x * 128);
}

// One block per 4 queries, 128 threads. XCD-aware: batch n = blockIdx.x & 7
// matches the round-robin block->XCD mapping, so each XCD's L2 holds one
// batch's value plane (2.8 MB f16 < 4 MB L2).
// NOTE (R1 post-mortem): 8-query/256-thread blocks raised occupancy 40->72%
// but doubled HBM fabric traffic (bval evicted from per-XCD L2 by the faster
// streaming flows) and regressed 75.7->92.8 us. The kernel is L2-locality-
// bound, not latency-bound: keep occupancy modest.
// Phase A (128 thr x 4 items = 512 = q4*h*l*p): coords + softmax + corner BYTE
//   offsets + packed-half2 weights -> LDS at slot = item idx (16B b128 writes).
// Phase B: thread = (q4, h, cg): 8 f16 channels per corner via uint4 loads;
//   4 v_pk_fma_f16 per corner; f32 flush every 4 iterations.
__global__ __launch_bounds__(128) void sample_kernel(
    const float* __restrict__ refp,            // (N, Lq, L, 2)
    const __half* __restrict__ off,            // (N*Lq, 256) f16
    const __half* __restrict__ attn,           // (N*Lq, 128) f16
    const __half* __restrict__ bval,           // (N, Lin, 256) f16, d = h*32+c
    const int* __restrict__ shapes,            // (L, 2) [H, W]
    const int* __restrict__ starts,            // (L,)
    ushort_t* __restrict__ sampb)              // (N*Lq, 256) bf16
{
    const int n = blockIdx.x & 7;
    const int qBase = n * NQ + (blockIdx.x >> 3) * 4;
    const int t = threadIdx.x;

    __shared__ __align__(16) int     sidx[512][4];   // 8 KB
    __shared__ __align__(16) __half2 sww[512][4];    // 8 KB

#pragma unroll
    for (int it = 0; it < 4; ++it) {
        const int i = t + it * 128;
        const int q4 = i >> 7, hlp = i & 127;
        const int h = hlp >> 4, lp = hlp & 15, l = lp >> 2;
        const int q = qBase + q4;
        const int Wl = shapes[2 * l + 1], Hl = shapes[2 * l];
        const float Wf = (float)Wl, Hf = (float)Hl;
        const float2 rp = *(const float2*)(refp + ((size_t)q * NLV + l) * 2);
        const __half2 oo2 = ((const __half2*)off)[(size_t)q * 128 + h * 16 + lp];
        const float2 oo = __half22float2(oo2);
        const float x = (rp.x + oo.x / Wf) * Wf - 0.5f;
        const float y = (rp.y + oo.y / Hf) * Hf - 0.5f;

        float logit = __half2float(attn[(size_t)q * 128 + h * 16 + lp]);
        float m = logit;
#pragma unroll
        for (int s = 8; s >= 1; s >>= 1) m = fmaxf(m, __shfl_xor(m, s, 16));
        float e = __expf(logit - m);
        float ss = e;
#pragma unroll
        for (int s = 8; s >= 1; s >>= 1) ss += __shfl_xor(ss, s, 16);
        const float aw = e / ss;

        const float xf = floorf(x), yf = floorf(y);
        const int ix = (int)xf, iy = (int)yf;
        const float wx = x - xf, wy = y - yf;
        const int ix1 = ix + 1, iy1 = iy + 1;
        const bool bx0 = (ix >= 0) & (ix < Wl);
        const bool bx1 = (ix1 >= 0) & (ix1 < Wl);
        const bool by0 = (iy >= 0) & (iy < Hl);
        const bool by1 = (iy1 >= 0) & (iy1 < Hl);
        const int cx0 = min(max(ix, 0), Wl - 1), cx1 = min(max(ix1, 0), Wl - 1);
        const int cy0 = min(max(iy, 0), Hl - 1), cy1 = min(max(iy1, 0), Hl - 1);
        const int base = n * NQ + starts[l];
        int4 id;
        id.x = (base + cy0 * Wl + cx0) << 9;   // byte offset (row stride 512B)
        id.y = (base + cy0 * Wl + cx1) << 9;
        id.z = (base + cy1 * Wl + cx0) << 9;
        id.w = (base + cy1 * Wl + cx1) << 9;
        __half2 wp[4];
        wp[0] = __float2half2_rn((bx0 && by0) ? aw * (1.f - wx) * (1.f - wy) : 0.f);
        wp[1] = __float2half2_rn((bx1 && by0) ? aw * wx * (1.f - wy) : 0.f);
        wp[2] = __float2half2_rn((bx0 && by1) ? aw * (1.f - wx) * wy : 0.f);
        wp[3] = __float2half2_rn((bx1 && by1) ? aw * wx * wy : 0.f);
        *(int4*)sidx[i] = id;
        *(uint4*)&sww[i][0] = *(uint4*)wp;
    }
    __syncthreads();

    const int q4 = t >> 5, r = t & 31;
    const int h = r >> 2, cg = r & 3;           // 8 channels per thread
    const int q = qBase + q4;
    const char* vb = (const char*)bval + h * 64 + cg * 16;

    __half2 acch[4];
    float accf[8];
#pragma unroll
    for (int e = 0; e < 4; ++e) acch[e] = __float2half2_rn(0.f);
#pragma unroll
    for (int e = 0; e < 8; ++e) accf[e] = 0.f;

#pragma unroll
    for (int j = 0; j < 16; ++j) {
        const int lp = (j + h) & 15;            // per-head rotation: 2-way max alias
        const int slot = (q4 << 7) + (h << 4) + lp;
        const int4 id = *(const int4*)sidx[slot];
        uint4 wu = *(const uint4*)&sww[slot][0];
        const __half2* wp = (const __half2*)&wu;
        int idc[4] = {id.x, id.y, id.z, id.w};
#pragma unroll
        for (int c = 0; c < 4; ++c) {
            const uint4 u = *(const uint4*)(vb + (size_t)(unsigned)idc[c]);
            const __half2* hv = (const __half2*)&u;
#pragma unroll
            for (int e = 0; e < 4; ++e) acch[e] = __hfma2(hv[e], wp[c], acch[e]);
        }
        if ((j & 3) == 3) {
#pragma unroll
            for (int e = 0; e < 4; ++e) {
                float2 f = __half22float2(acch[e]);
                accf[2 * e] += f.x;
                accf[2 * e + 1] += f.y;
                acch[e] = __float2half2_rn(0.f);
            }
        }
    }

    s16x8 o;
#pragma unroll
    for (int e = 0; e < 8; ++e) o[e] = f2bf(accf[e]);
    *(s16x8*)(sampb + (size_t)q * DIM + h * CHN + cg * 8) = o;
}

extern "C" void kernel_launch(void* const* d_in, const int* in_sizes, int n_in,
                              void* d_out, int out_size, void* d_ws, size_t ws_size,
                              hipStream_t stream) {
    const float* query  = (const float*)d_in[0];
    const float* refp   = (const float*)d_in[1];
    const float* inputf = (const float*)d_in[2];
    const int* shapes   = (const int*)d_in[3];
    const int* starts   = (const int*)d_in[4];
    const float* W_off  = (const float*)d_in[5];
    const float* b_off  = (const float*)d_in[6];
    const float* W_attn = (const float*)d_in[7];
    const float* b_attn = (const float*)d_in[8];
    const float* W_val  = (const float*)d_in[9];
    const float* b_val  = (const float*)d_in[10];
    const float* W_out  = (const float*)d_in[11];
    const float* b_out  = (const float*)d_in[12];
    float* out = (float*)d_out;

    // workspace (bytes): wb(bf16) | bval(f16) | v_off(f16) | v_attn(f16) |
    //                    sampb(bf16) | qb(bf16)
    // ib(bf16, 22.3 MB) lives in the FIRST HALF OF d_out (44.6 MB fp32):
    // d_out is dead until gemm_out overwrites it, and gemm_all consumes ib
    // strictly before gemm_out runs (same stream).
    const size_t AB = (size_t)MTOT * DIM * 2;   // 22,282,240
    char* ws = (char*)d_ws;
    ushort_t* wb     = (ushort_t*)ws;                                   // 0.46 MB
    __half*   bval   = (__half*)(ws + 512 * 1024);
    __half*   v_off  = (__half*)(ws + 512 * 1024 + AB);
    __half*   v_attn = (__half*)(ws + 512 * 1024 + 2 * AB);
    ushort_t* sampb  = (ushort_t*)(ws + 512 * 1024 + 2 * AB + AB / 2);
    ushort_t* qb     = (ushort_t*)(ws + 512 * 1024 + 3 * AB + AB / 2);
    ushort_t* ib     = (ushort_t*)d_out;

    const int cvtBlocks = (WTOT + 2 * QTOT) / 2048;   // 10992 exactly
    cvt_all<<<dim3(cvtBlocks), dim3(256), 0, stream>>>(W_val, W_off, W_attn, W_out,
                                                       query, inputf, wb, qb, ib);
    gemm_all<<<dim3(1024), dim3(256), 0, stream>>>(qb, ib, wb, b_val, b_off, b_attn,
                                                   bval, v_off, v_attn);
    sample_kernel<<<dim3(MTOT / 4), dim3(128), 0, stream>>>(
        refp, v_off, v_attn, bval, shapes, starts, sampb);
    gemm_out<<<dim3(340, 2), dim3(256), 0, stream>>>(sampb, wb, b_out, out);
}